// Round 11
// baseline (5838.773 us; speedup 1.0000x reference)
//
#include <hip/hip_runtime.h>
#include <math.h>

#define N 64
#define P 32                       // Brent-Luk processors (lanes) per matrix
#define TRI ((N * (N + 1)) / 2)    // 2080
#define MAX_SWEEPS 20
#define TOL2 1e-10f                // proven (R3/R9/R10): fires ~11 sweeps, floor accuracy
#define WS_PER_MAT (N * N + N)
#define WPB 2                      // waves/block = 4 matrices/block

// One DPP lane-move. ctrl is a compile-time DPP control code.
// bound_ctrl=false + old=x: lanes with invalid source keep x (all such lanes
// are overridden by cndmask below anyway).
template <int CTRL>
__device__ __forceinline__ float dppmov(float x) {
    return __int_as_float(__builtin_amdgcn_update_dpp(
        __float_as_int(x), __float_as_int(x), CTRL, 0xF, 0xF, false));
}

// ---------------------------------------------------------------------------
// Brent-Luk one-sided Jacobi: lane j (of its 32-lane half) owns columns
// u (slot T_j) and v (slot B_j) ENTIRELY in registers. Rotation pair =
// (u,v) in-lane: dot/rotation/norms need no cross-lane ops at all (and the
// R6/R7 tie-coherence bug class is structurally impossible).
// Tournament movement per round (T0 fixed, single 63-cycle -> identity after
// each 63-round sweep, all 2016 pairs covered):
//   newT[j] = T'[j-1] (j>=2), newT[1] = B'[0], T'[0] stays,
//   newB[j] = B'[j+1] (j<=30), newB[31] = T'[31].
// Realized with semantic UP (D[i]=S[i-1]) / DOWN (D[i]=S[i+1]) wave-DPP
// shifts; which ctrl code (0x130/0x138) is UP is resolved by a runtime probe.
// Wave holds 2 matrices (lanes 0-31, 32-63): every cross-matrix leak of a
// wave-wide shift lands exactly on a cndmask'd lane (j==0, j==1, j==31).
// ---------------------------------------------------------------------------
template <int CTRL_UP, int CTRL_DOWN>
__device__ __forceinline__ void bl_sweeps(float u[N], float v[N],
                                          bool is0, bool is1, bool is31) {
    #pragma unroll 1
    for (int sw = 0; sw < MAX_SWEEPS; ++sw) {
        // fresh norms at sweep start (tracked in between)
        float a0 = 0.f, a1 = 0.f, a2 = 0.f, a3 = 0.f;
        float b0 = 0.f, b1 = 0.f, b2 = 0.f, b3 = 0.f;
        #pragma unroll
        for (int k = 0; k < N; k += 4) {
            a0 = fmaf(u[k],     u[k],     a0);
            a1 = fmaf(u[k + 1], u[k + 1], a1);
            a2 = fmaf(u[k + 2], u[k + 2], a2);
            a3 = fmaf(u[k + 3], u[k + 3], a3);
            b0 = fmaf(v[k],     v[k],     b0);
            b1 = fmaf(v[k + 1], v[k + 1], b1);
            b2 = fmaf(v[k + 2], v[k + 2], b2);
            b3 = fmaf(v[k + 3], v[k + 3], b3);
        }
        float nu = (a0 + a1) + (a2 + a3);
        float nv = (b0 + b1) + (b2 + b3);
        int bad = 0;
        #pragma unroll 1
        for (int r = 0; r < 63; ++r) {
            // --- in-lane dot (4 independent chains)
            float d0 = 0.f, d1 = 0.f, d2 = 0.f, d3 = 0.f;
            #pragma unroll
            for (int k = 0; k < N; k += 4) {
                d0 = fmaf(u[k],     v[k],     d0);
                d1 = fmaf(u[k + 1], v[k + 1], d1);
                d2 = fmaf(u[k + 2], v[k + 2], d2);
                d3 = fmaf(u[k + 3], v[k + 3], d3);
            }
            const float d = (d0 + d1) + (d2 + d3);
            bad |= (d * d > TOL2 * nu * nv);
            // --- in-lane rotation params (no role select needed: one owner)
            float c = 1.f, s = 0.f, tt = 0.f;
            if (fabsf(d) > 1e-36f) {
                const float tau = (nv - nu) / (2.f * d);
                tt = copysignf(
                    1.f / (fabsf(tau) + sqrtf(fmaf(tau, tau, 1.f))), tau);
                c = rsqrtf(fmaf(tt, tt, 1.f));
                s = tt * c;
            }
            nu = fmaf(-tt, d, nu);   // nu' = nu - t*d (trace preserved)
            nv = fmaf( tt, d, nv);
            // --- fused rotate + move (per row: 4 VALU rot, 3 DPP, 3 cndmask)
            #pragma unroll
            for (int k = 0; k < N; ++k) {
                const float un = fmaf(-s, v[k], c * u[k]);  // u' = c u - s v
                const float vn = fmaf( s, u[k], c * v[k]);  // v' = s u + c v
                const float tu = dppmov<CTRL_UP>(un);    // lane j <- u'[j-1]
                const float tv = dppmov<CTRL_UP>(vn);    // lane 1 <- v'[0]
                const float tw = dppmov<CTRL_DOWN>(vn);  // lane j <- v'[j+1]
                float uu = is1 ? tv : tu;
                uu = is0 ? un : uu;                      // T0 fixed
                v[k] = is31 ? un : tw;                   // B31 <- own u'
                u[k] = uu;
            }
            // --- move tracked norms along the same cycle
            {
                const float tu = dppmov<CTRL_UP>(nu);
                const float tv = dppmov<CTRL_UP>(nv);
                const float tw = dppmov<CTRL_DOWN>(nv);
                float uu = is1 ? tv : tu;
                uu = is0 ? nu : uu;
                nv = is31 ? nu : tw;
                nu = uu;
            }
        }
        if (!__any(bad)) break;   // sweep ends at identity arrangement
    }
}

// Phase 1: zero LDS, zero DS-pipe ops, no barriers. 2 matrices per wave.
__global__ __launch_bounds__(64 * WPB)
void jacobi_bl_kernel(const float* __restrict__ X, float* __restrict__ ws) {
    const int lane = threadIdx.x & 63;
    const int wid  = threadIdx.x >> 6;
    const int j    = lane & 31;
    const int b    = blockIdx.x * (2 * WPB) + wid * 2 + (lane >> 5);
    const float* __restrict__ Xb = X + (size_t)b * (N * N);

    // lane j owns columns 2j (u) and 2j+1 (v): coalesced float2 row loads
    float u[N], v[N];
    #pragma unroll
    for (int k = 0; k < N; ++k) {
        const float2 ld = *(const float2*)(Xb + k * N + 2 * j);
        u[k] = ld.x; v[k] = ld.y;
    }
    const bool is0 = (j == 0), is1 = (j == 1), is31 = (j == 31);

    // Probe which DPP ctrl is the semantic UP (D[i]=S[i-1]): if 0x138 is UP,
    // lane1's probe value is lane0's id = 0. Wave-uniform -> uniform branch.
    const int probe = __builtin_amdgcn_update_dpp(lane, lane, 0x138, 0xF, 0xF, false);
    const bool shr_is_up = (__builtin_amdgcn_readlane(probe, 1) == 0);
    if (shr_is_up) bl_sweeps<0x138, 0x130>(u, v, is0, is1, is31);
    else           bl_sweeps<0x130, 0x138>(u, v, is0, is1, is31);

    // fresh final norms -> weights; store G row-major as float2 (coalesced)
    float a0 = 0.f, a1 = 0.f, a2 = 0.f, a3 = 0.f;
    float b0 = 0.f, b1 = 0.f, b2 = 0.f, b3 = 0.f;
    #pragma unroll
    for (int k = 0; k < N; k += 4) {
        a0 = fmaf(u[k],     u[k],     a0);
        a1 = fmaf(u[k + 1], u[k + 1], a1);
        a2 = fmaf(u[k + 2], u[k + 2], a2);
        a3 = fmaf(u[k + 3], u[k + 3], a3);
        b0 = fmaf(v[k],     v[k],     b0);
        b1 = fmaf(v[k + 1], v[k + 1], b1);
        b2 = fmaf(v[k + 2], v[k + 2], b2);
        b3 = fmaf(v[k + 3], v[k + 3], b3);
    }
    const float nu = (a0 + a1) + (a2 + a3);
    const float nv = (b0 + b1) + (b2 + b3);
    float* __restrict__ wb = ws + (size_t)b * WS_PER_MAT;
    #pragma unroll
    for (int k = 0; k < N; ++k) {
        float2 st; st.x = u[k]; st.y = v[k];
        *(float2*)(wb + k * N + 2 * j) = st;
    }
    float su = sqrtf(nu); su = fminf(fmaxf(su, 1e-4f), 1e4f);
    float sv = sqrtf(nv); sv = fminf(fmaxf(sv, 1e-4f), 1e4f);
    wb[N * N + 2 * j]     = logf(su) / fmaxf(nu, 1e-12f);
    wb[N * N + 2 * j + 1] = logf(sv) / fmaxf(nv, 1e-12f);
}

// Phase 2: logm[i][j] = sum_t w_t S[i][t] S[j][t] (unchanged, R10-proven).
__global__ __launch_bounds__(256)
void outer_kernel(const float* __restrict__ ws, float* __restrict__ out) {
    __shared__ float S[N][N + 1];
    __shared__ float wv[N];
    const int b = blockIdx.x;
    const int tid = threadIdx.x;
    const float* __restrict__ wb = ws + (size_t)b * WS_PER_MAT;
    for (int idx = tid; idx < N * N; idx += 256)
        S[idx >> 6][idx & 63] = wb[idx];
    if (tid < N) wv[tid] = wb[N * N + tid];
    __syncthreads();
    const int tx = tid & 15, ty = tid >> 4;
    const int i0 = ty * 4, j0 = tx * 4;
    float acc[4][4];
    #pragma unroll
    for (int r = 0; r < 4; ++r)
        #pragma unroll
        for (int c_ = 0; c_ < 4; ++c_) acc[r][c_] = 0.f;
    #pragma unroll 8
    for (int t = 0; t < N; ++t) {
        const float w = wv[t];
        float si[4], sj[4];
        #pragma unroll
        for (int r = 0; r < 4; ++r) si[r] = w * S[i0 + r][t];
        #pragma unroll
        for (int c_ = 0; c_ < 4; ++c_) sj[c_] = S[j0 + c_][t];
        #pragma unroll
        for (int r = 0; r < 4; ++r)
            #pragma unroll
            for (int c_ = 0; c_ < 4; ++c_)
                acc[r][c_] = fmaf(si[r], sj[c_], acc[r][c_]);
    }
    float* __restrict__ ob = out + (size_t)b * TRI;
    #pragma unroll
    for (int r = 0; r < 4; ++r) {
        const int i = i0 + r;
        const int st = i * (2 * N + 1 - i) / 2;
        #pragma unroll
        for (int c_ = 0; c_ < 4; ++c_) {
            const int j = j0 + c_;
            if (j >= i) ob[st + (j - i)] = acc[r][c_];
        }
    }
}

// ---------------------------------------------------------------------------
// Fallback (ws too small): R8/R9-proven 1-wave bperm kernel, fused epilogue.
// ---------------------------------------------------------------------------
__device__ __forceinline__ float bperm(int byte_addr, float val) {
    return __int_as_float(
        __builtin_amdgcn_ds_bpermute(byte_addr, __float_as_int(val)));
}

__global__ __launch_bounds__(64)
void fused_kernel(const float* __restrict__ X, float* __restrict__ out) {
    __shared__ float Gt[N][N + 1];
    __shared__ float w[N];
    const int b = blockIdx.x;
    const int t = threadIdx.x;
    const int self4 = t << 2;
    const float* __restrict__ Xb = X + (size_t)b * (N * N);
    float g[N];
    #pragma unroll
    for (int k = 0; k < N; ++k) g[k] = Xb[k * N + t];
    for (int sw = 0; sw < MAX_SWEEPS; ++sw) {
        float n0 = 0.f, n1 = 0.f, n2 = 0.f, n3 = 0.f;
        #pragma unroll
        for (int k = 0; k < N; k += 4) {
            n0 = fmaf(g[k],     g[k],     n0);
            n1 = fmaf(g[k + 1], g[k + 1], n1);
            n2 = fmaf(g[k + 2], g[k + 2], n2);
            n3 = fmaf(g[k + 3], g[k + 3], n3);
        }
        float na = (n0 + n1) + (n2 + n3);
        int bad = 0;
        for (int m = 1; m < N; ++m) {
            const int pa = self4 ^ (m << 2);
            const bool lower = (self4 < pa);
            float pt[N];
            float d0 = 0.f, d1 = 0.f, d2 = 0.f, d3 = 0.f;
            #pragma unroll
            for (int k = 0; k < N; k += 4) {
                pt[k]     = bperm(pa, g[k]);
                pt[k + 1] = bperm(pa, g[k + 1]);
                pt[k + 2] = bperm(pa, g[k + 2]);
                pt[k + 3] = bperm(pa, g[k + 3]);
                d0 = fmaf(g[k],     pt[k],     d0);
                d1 = fmaf(g[k + 1], pt[k + 1], d1);
                d2 = fmaf(g[k + 2], pt[k + 2], d2);
                d3 = fmaf(g[k + 3], pt[k + 3], d3);
            }
            const float d  = (d0 + d1) + (d2 + d3);
            const float nb = bperm(pa, na);
            bad |= (d * d > TOL2 * na * nb);
            const float nlo = lower ? na : nb;
            const float nhi = lower ? nb : na;
            float c = 1.f, s = 0.f, tt = 0.f;
            if (fabsf(d) > 1e-36f) {
                const float tau = (nhi - nlo) / (2.f * d);
                tt = copysignf(
                    1.f / (fabsf(tau) + sqrtf(fmaf(tau, tau, 1.f))), tau);
                c = rsqrtf(fmaf(tt, tt, 1.f));
                s = tt * c;
            }
            const float se = lower ? -s : s;
            const float st = lower ? -tt : tt;
            na = fmaf(st, d, na);
            #pragma unroll
            for (int k = 0; k < N; ++k) g[k] = fmaf(se, pt[k], c * g[k]);
        }
        if (!__any(bad)) break;
    }
    float nown = 0.f;
    #pragma unroll
    for (int k = 0; k < N; ++k) {
        Gt[t][k] = g[k];
        nown = fmaf(g[k], g[k], nown);
    }
    float sv = sqrtf(nown);
    sv = fminf(fmaxf(sv, 1e-4f), 1e4f);
    w[t] = logf(sv) / fmaxf(nown, 1e-12f);
    __syncthreads();
    float wr[N];
    #pragma unroll
    for (int k = 0; k < N; ++k) wr[k] = w[k];
    float* __restrict__ ob = out + (size_t)b * TRI;
    int i = 0, base = 0;
    for (int e = t; e < TRI; e += N) {
        while (base + (N - i) <= e) { base += (N - i); ++i; }
        const int jj = i + (e - base);
        float acc = 0.f;
        #pragma unroll
        for (int k = 0; k < N; ++k)
            acc = fmaf(wr[k] * Gt[k][i], Gt[k][jj], acc);
        ob[e] = acc;
    }
}

extern "C" void kernel_launch(void* const* d_in, const int* in_sizes, int n_in,
                              void* d_out, int out_size, void* d_ws, size_t ws_size,
                              hipStream_t stream) {
    const float* x = (const float*)d_in[0];
    float* out = (float*)d_out;
    const int B = in_sizes[0] / (N * N);   // 8192
    const size_t need = (size_t)B * WS_PER_MAT * sizeof(float);  // ~136 MB
    if (ws_size >= need && (B % (2 * WPB)) == 0) {
        jacobi_bl_kernel<<<dim3(B / (2 * WPB)), dim3(64 * WPB), 0, stream>>>(
            x, (float*)d_ws);
        outer_kernel<<<dim3(B), dim3(256), 0, stream>>>((const float*)d_ws, out);
    } else {
        fused_kernel<<<dim3(B), dim3(64), 0, stream>>>(x, out);
    }
}